// Round 6
// baseline (598.451 us; speedup 1.0000x reference)
//
#include <hip/hip_runtime.h>
#include <cstdint>
#include <cstddef>

typedef __bf16 bf16x8 __attribute__((ext_vector_type(8)));
typedef __bf16 bf16x4 __attribute__((ext_vector_type(4)));
typedef float  f32x4  __attribute__((ext_vector_type(4)));

#define MFMA16(a,b,c) __builtin_amdgcn_mfma_f32_16x16x32_bf16((a),(b),(c),0,0,0)

// LDS-only barrier: per-step ring handoff needs lgkmcnt(0) only.
// Global stores drained explicitly at publish points (BAR_FULL, rec waves).
#define BAR_LGKM() __asm__ volatile("s_waitcnt lgkmcnt(0)\n\ts_barrier" ::: "memory")
#define BAR_FULL() __asm__ volatile("s_waitcnt vmcnt(0) lgkmcnt(0)\n\ts_barrier" ::: "memory")

#define L2E  1.4426950408889634f   // log2(e)
#define L2E2 2.8853900817779268f   // 2*log2(e)

// Problem: B=256, T=512, D=H=128, 3H=384. x/out batch stride = 65536 elems.
// 32 blocks x 1024 threads: 0..15 layer 0 (producer), 16..31 layer 1
// (consumer, lagged). h0 crosses XCDs via nt stores/loads + per-pair
// agent-scope flags.
//
// Round-6: WAVE SPECIALIZATION. Round-5 was register-locked at 2 waves/SIMD
// (24 pinned weight frags = 96 regs + acc + A-frags ~190/wave): every
// post-barrier LDS burst / MFMA tail / barrier entry exposed. Split roles:
//   waves 0..7  (xp):  W-frags only. Compute xp_{t+1} = input_{t+1}*W,
//                      write f32 to LDS ring pp; stage input tiles; poll
//                      flags (layer 1). ~115 regs.
//   waves 8..15 (rec): U-frags only. C-init z/r from pp, 12 rec MFMAs,
//                      epilogue, h ring write, global stores. ~125 regs.
// -> __launch_bounds__(1024,4): 4 waves/SIMD (2 xp + 2 rec): heterogeneous
// SIMD-mates, rec VALU overlaps xp MFMA. Bit-identical numerics (xp f32
// round-trips LDS exactly; same accumulation order as round 5).

// ---------------------------------------------------------------------------
// prep_frags: stacked-weight B-frags, K=256 ([W(128) ; U(128)]), + flag init.
// Frag layout (16x16x32): B[k][n], n = lane&15, k = kt*32 + (lane>>4)*8 + j.
// Elem offset = ((ct*8+kt)*64 + lane)*8 + j, ct 0..23 (z:0-7,r:8-15,h:16-23),
// kt 0..7 (kt<4 -> W rows k, kt>=4 -> U rows k-128). Per layer: 98304 bf16.
// Values pre-scaled: L2E for z/r cols (ct<16), L2E2 for h cols (ct>=16).
// ---------------------------------------------------------------------------
__global__ void prep_frags(const float* __restrict__ W0, const float* __restrict__ U0,
                           const float* __restrict__ W1, const float* __restrict__ U1,
                           __bf16* __restrict__ frags, int* __restrict__ flags)
{
    if (blockIdx.x == 0 && threadIdx.x < 16) flags[threadIdx.x * 16] = 0;
    int id = blockIdx.x * 512 + threadIdx.x;      // 0..24575
    int layer = id / 12288;
    int r     = id % 12288;                       // (ct*8+kt)*64 + lane
    int lane = r & 63;
    int ctkt = r >> 6;                            // 0..191
    int kt = ctkt & 7;
    int ct = ctkt >> 3;
    const float* Wsrc = layer ? W1 : W0;
    const float* Usrc = layer ? U1 : U0;
    int n  = ct * 16 + (lane & 15);
    int k0 = kt * 32 + (lane >> 4) * 8;           // never straddles 128
    const float* src = (k0 < 128) ? (Wsrc + (size_t)k0 * 384)
                                  : (Usrc + (size_t)(k0 - 128) * 384);
    const float s = (ct < 16) ? L2E : L2E2;       // z,r vs h columns
    __bf16* dst = frags + (size_t)layer * 98304 + (size_t)r * 8;
#pragma unroll
    for (int j = 0; j < 8; j++)
        dst[j] = (__bf16)(src[(size_t)j * 384 + n] * s);
}

// ---------------------------------------------------------------------------
// gru_pipe: per block 16 batch rows, 1024 threads (16 waves). Ring state at
// step t (all depth-2, one barrier/step):
//   pp[t&1] = xp_t (f32, C-layout), hb[t&1] = h_{t-1}, xb[t&1] = input_{t+1}.
// xp-wave step t: read xb[cur] -> xp_{t+1} -> pp[nxt]; stage input_{t+2}
//   (vc, loaded last step) -> xb[nxt]; load input_{t+3} (layer 1: gated
//   flag >= t+4). rec-wave step t: read hb[cur] + pp[cur], 12 U-MFMAs,
//   epilogue, h_t -> hb[nxt] + global.
// Producer publish: flag=t every 4th step (rec waves vmcnt(0) before the
// barrier, xp lane 0 stores after it): asserts h0 steps <= t-1 in HBM.
// h0 may alias out (small-ws fallback): consumer reads slot t+3 strictly
// before overwriting slot t. No __restrict__ on x/h0/out.
// ---------------------------------------------------------------------------
__global__ __launch_bounds__(1024, 4) void gru_pipe(
    const float* x, const __bf16* __restrict__ frags,
    const float* __restrict__ b0, const float* __restrict__ b1,
    float* h0, float* out, int* flags)
{
    __shared__ __align__(16) __bf16 xb[2][2048];   // input tile ring (bf16)
    __shared__ __align__(16) __bf16 hb[2][2048];   // h ring (bf16)
    __shared__ __align__(16) float  pp[2][6144];   // xp ring (f32, C-layout)

    const int tid  = threadIdx.x;
    const int wave = tid >> 6, lane = tid & 63;
    const int l15  = lane & 15, quad = lane >> 4;
    const bool is_xp = (wave < 8);
    const int  w8   = wave & 7;
    const int pair  = blockIdx.x & 15;
    const int layer = blockIdx.x >> 4;
    const int B0 = pair * 16;
    int* const flagp = flags + pair * 16;          // one 64B line per pair

    const __bf16* Bf  = frags + (size_t)layer * 98304;
    const float* bias = layer ? b1 : b0;
    const float* xin  = layer ? h0 : x;
    float*       hout = layer ? out : h0;

    // role frags: xp waves take W (kt 0..3), rec waves take U (kt 4..7).
    // Pinned so loads can't be sunk into the t-loop (round-4 lesson).
    const int ktoff = is_xp ? 0 : 4;
    bf16x8 bf_[3][4];
#pragma unroll
    for (int g = 0; g < 3; g++) {
        int ct = 8 * g + w8;
#pragma unroll
        for (int kt = 0; kt < 4; kt++) {
            bf_[g][kt] = *(const bf16x8*)(Bf + (size_t)((ct * 8 + kt + ktoff) * 64 + lane) * 8);
            __asm__ volatile("" : "+v"(bf_[g][kt]));
        }
    }

    const int j = w8 * 16 + l15;
    const float bz  = (bias[j]       + bias[384 + j]) * L2E;
    const float br  = (bias[128 + j] + bias[512 + j]) * L2E;
    const float bxh = bias[256 + j] * L2E2;
    const float brh = bias[640 + j] * L2E2;

    // staging map (xp waves = tid<512): 16 rows x 128 cols, 4 f32/thread
    const int srow = tid >> 5;
    const float* px = xin + (size_t)(B0 + (srow & 15)) * 65536 + (tid & 31) * 4;
    const int sb = ((srow & 15) * 256 + (tid & 31) * 8) ^ ((srow & 7) << 4);

    // A-frag byte offsets (swizzled), shared by xb (xp) and hb (rec) reads
    const int swz = (l15 & 7) << 4;
    const int abb = l15 * 256 + quad * 16;
    const int ao0 = (abb      ) ^ swz;
    const int ao1 = (abb +  64) ^ swz;
    const int ao2 = (abb + 128) ^ swz;
    const int ao3 = (abb + 192) ^ swz;
    // h-write byte offsets (rec waves; scalar bf16, row = quad*4+r, col j)
    int hw_[4];
#pragma unroll
    for (int r = 0; r < 4; r++) {
        int row = quad * 4 + r;
        hw_[r] = (row * 256 + j * 2) ^ ((row & 7) << 4);
    }
    // pp element offset: gate g at g*2048 + w8*256 + lane*4 (f32 elems)
    const int ppo = w8 * 256 + lane * 4;

    const size_t obase = (size_t)(B0 + quad * 4) * 65536 + j;

#define LOADX(p) (layer ? __builtin_nontemporal_load((const f32x4*)(p)) \
                        : *(const f32x4*)(p))
#define PACKST(buf, v) do { bf16x4 hv_;                                  \
        hv_.x = (__bf16)(v)[0]; hv_.y = (__bf16)(v)[1];                  \
        hv_.z = (__bf16)(v)[2]; hv_.w = (__bf16)(v)[3];                  \
        *(bf16x4*)((char*)&(buf)[0] + sb) = hv_; } while (0)

    const f32x4 zv = {0.f, 0.f, 0.f, 0.f};
    f32x4 vc = zv;
    int known = 0;

    // ---- prologue ----
    if (layer && is_xp) {                 // prologue loads input_0..2
        while (known < 3) {
            __builtin_amdgcn_s_sleep(4);
            known = __hip_atomic_load(flagp, __ATOMIC_RELAXED,
                                      __HIP_MEMORY_SCOPE_AGENT);
        }
    }
    if (is_xp) {
        f32x4 v0 = LOADX(px);             // input_0
        PACKST(xb[0], v0);
    } else {
        ((uint64_t*)&hb[0][0])[tid & 511] = 0ull;   // h_{-1} = 0
    }
    __syncthreads();
    if (is_xp) {                          // xp_0 -> pp[0]
        bf16x8 A0 = *(const bf16x8*)((const char*)&xb[0][0] + ao0);
        bf16x8 A1 = *(const bf16x8*)((const char*)&xb[0][0] + ao1);
        bf16x8 A2 = *(const bf16x8*)((const char*)&xb[0][0] + ao2);
        bf16x8 A3 = *(const bf16x8*)((const char*)&xb[0][0] + ao3);
        f32x4 cz = zv, cr = zv, ch = zv;
        cz = MFMA16(A0, bf_[0][0], cz); cr = MFMA16(A0, bf_[1][0], cr); ch = MFMA16(A0, bf_[2][0], ch);
        cz = MFMA16(A1, bf_[0][1], cz); cr = MFMA16(A1, bf_[1][1], cr); ch = MFMA16(A1, bf_[2][1], ch);
        cz = MFMA16(A2, bf_[0][2], cz); cr = MFMA16(A2, bf_[1][2], cr); ch = MFMA16(A2, bf_[2][2], ch);
        cz = MFMA16(A3, bf_[0][3], cz); cr = MFMA16(A3, bf_[1][3], cr); ch = MFMA16(A3, bf_[2][3], ch);
        *(f32x4*)&pp[0][ppo]        = cz;
        *(f32x4*)&pp[0][2048 + ppo] = cr;
        *(f32x4*)&pp[0][4096 + ppo] = ch;
    }
    BAR_LGKM();                           // pp[0] ready; xb[0] reads done
    if (is_xp) {
        f32x4 v1 = LOADX(px + 128);       // input_1 -> xb[0] (step-0 source)
        PACKST(xb[0], v1);
        vc = LOADX(px + 256);             // input_2 (staged at t=0)
    }
    float hold[4] = {0.f, 0.f, 0.f, 0.f};
    BAR_LGKM();                           // xb[0] restaged

    // ---- main loop: one barrier per step ----
    for (int t = 0; t < 512; ++t) {
        const int cur = t & 1, nxt = cur ^ 1;

        if (is_xp) {
            if (layer) {                  // gate input_{t+3} load
                int need = t + 4; if (need > 512) need = 512;
                while (known < need) {
                    __builtin_amdgcn_s_sleep(4);
                    known = __hip_atomic_load(flagp, __ATOMIC_RELAXED,
                                              __HIP_MEMORY_SCOPE_AGENT);
                }
            }
            const int t3 = (t < 509) ? (t + 3) : 511;
            f32x4 vn = LOADX(px + (size_t)t3 * 128);

            // xp_{t+1} = input_{t+1} * W  -> pp[nxt]
            bf16x8 A0 = *(const bf16x8*)((const char*)&xb[cur][0] + ao0);
            bf16x8 A1 = *(const bf16x8*)((const char*)&xb[cur][0] + ao1);
            bf16x8 A2 = *(const bf16x8*)((const char*)&xb[cur][0] + ao2);
            bf16x8 A3 = *(const bf16x8*)((const char*)&xb[cur][0] + ao3);
            f32x4 cz = zv, cr = zv, ch = zv;
            cz = MFMA16(A0, bf_[0][0], cz); cr = MFMA16(A0, bf_[1][0], cr); ch = MFMA16(A0, bf_[2][0], ch);
            cz = MFMA16(A1, bf_[0][1], cz); cr = MFMA16(A1, bf_[1][1], cr); ch = MFMA16(A1, bf_[2][1], ch);
            cz = MFMA16(A2, bf_[0][2], cz); cr = MFMA16(A2, bf_[1][2], cr); ch = MFMA16(A2, bf_[2][2], ch);
            cz = MFMA16(A3, bf_[0][3], cz); cr = MFMA16(A3, bf_[1][3], cr); ch = MFMA16(A3, bf_[2][3], ch);
            *(f32x4*)&pp[nxt][ppo]        = cz;
            *(f32x4*)&pp[nxt][2048 + ppo] = cr;
            *(f32x4*)&pp[nxt][4096 + ppo] = ch;

            PACKST(xb[nxt], vc);          // stage input_{t+2}
            vc = vn;

            BAR_LGKM();
            if (layer == 0 && (t & 3) == 3 && tid == 0)
                __hip_atomic_store(flagp, t, __ATOMIC_RELAXED,
                                   __HIP_MEMORY_SCOPE_AGENT);
        } else {
            // recurrent: h_{t-1} frags + xp_t C-init from rings
            bf16x8 A0 = *(const bf16x8*)((const char*)&hb[cur][0] + ao0);
            bf16x8 A1 = *(const bf16x8*)((const char*)&hb[cur][0] + ao1);
            bf16x8 A2 = *(const bf16x8*)((const char*)&hb[cur][0] + ao2);
            bf16x8 A3 = *(const bf16x8*)((const char*)&hb[cur][0] + ao3);
            f32x4 az  = *(const f32x4*)&pp[cur][ppo];
            f32x4 ar  = *(const f32x4*)&pp[cur][2048 + ppo];
            f32x4 xh  = *(const f32x4*)&pp[cur][4096 + ppo];
            f32x4 ahh = zv;
            __builtin_amdgcn_s_setprio(1);
            az = MFMA16(A0, bf_[0][0], az); ar = MFMA16(A0, bf_[1][0], ar); ahh = MFMA16(A0, bf_[2][0], ahh);
            az = MFMA16(A1, bf_[0][1], az); ar = MFMA16(A1, bf_[1][1], ar); ahh = MFMA16(A1, bf_[2][1], ahh);
            az = MFMA16(A2, bf_[0][2], az); ar = MFMA16(A2, bf_[1][2], ar); ahh = MFMA16(A2, bf_[2][2], ahh);
            az = MFMA16(A3, bf_[0][3], az); ar = MFMA16(A3, bf_[1][3], ar); ahh = MFMA16(A3, bf_[2][3], ahh);
            __builtin_amdgcn_s_setprio(0);

            // epilogue (pre-scaled by log2e/2log2e -> raw 2^x)
            float hnew[4];
#pragma unroll
            for (int r = 0; r < 4; r++) {
                float z  = __builtin_amdgcn_rcpf(
                               1.f + __builtin_amdgcn_exp2f(-(az[r] + bz)));
                float rg = __builtin_amdgcn_rcpf(
                               1.f + __builtin_amdgcn_exp2f(-(ar[r] + br)));
                float hp = (xh[r] + bxh) + rg * (ahh[r] + brh);
                float e2 = __builtin_amdgcn_exp2f(hp);
                float th = 1.f - 2.f * __builtin_amdgcn_rcpf(e2 + 1.f);
                hnew[r] = th + z * (hold[r] - th);
                hold[r] = hnew[r];
            }

            // h_t -> LDS ring
#pragma unroll
            for (int r = 0; r < 4; r++)
                *(__bf16*)((char*)&hb[nxt][0] + hw_[r]) = (__bf16)hnew[r];

            // barrier: lgkm-only normally; full drain on publish steps
            if (layer == 0 && (t & 3) == 3) {
                BAR_FULL();               // h0 stores of steps <= t-1 in HBM
            } else {
                BAR_LGKM();
            }

            // h_t -> global (drains during subsequent steps)
            if (layer == 0) {
#pragma unroll
                for (int r = 0; r < 4; r++)
                    __builtin_nontemporal_store(hnew[r],
                        hout + obase + (size_t)r * 65536 + (size_t)t * 128);
            } else {
#pragma unroll
                for (int r = 0; r < 4; r++)
                    hout[obase + (size_t)r * 65536 + (size_t)t * 128] = hnew[r];
            }
        }
    }

    if (layer == 0) {
        if (is_xp) { BAR_LGKM(); } else { BAR_FULL(); }   // drain final h0 stores
        if (tid == 0)
            __hip_atomic_store(flagp, 512, __ATOMIC_RELAXED,
                               __HIP_MEMORY_SCOPE_AGENT);
    }
#undef PACKST
#undef LOADX
}

// ---------------------------------------------------------------------------
extern "C" void kernel_launch(void* const* d_in, const int* in_sizes, int n_in,
                              void* d_out, int out_size, void* d_ws, size_t ws_size,
                              hipStream_t stream)
{
    const float* x  = (const float*)d_in[0];
    const float* W0 = (const float*)d_in[1];
    const float* U0 = (const float*)d_in[2];
    const float* b0 = (const float*)d_in[3];
    const float* W1 = (const float*)d_in[4];
    const float* U1 = (const float*)d_in[5];
    const float* b1 = (const float*)d_in[6];
    float* out = (float*)d_out;

    char* ws = (char*)d_ws;
    __bf16* frags = (__bf16*)ws;                 // 2 * 98304 bf16 = 393,216 B
    int*    flags = (int*)(ws + 393216);         // 16 pairs x 64 B = 1024 B
    // h0 at ws + 448 KiB if it fits, else alias d_out (pipeline-safe: consumer
    // reads slot t+3 strictly before overwriting slot t).
    float* h0;
    const size_t need = 458752 + 67108864;
    if (ws_size >= need) h0 = (float*)(ws + 458752);
    else                 h0 = out;

    prep_frags<<<48, 512, 0, stream>>>(W0, U0, W1, U1, frags, flags);
    gru_pipe<<<32, 1024, 0, stream>>>(x, frags, b0, b1, h0, out, flags);
}

// Round 7
// 590.084 us; speedup vs baseline: 1.0142x; 1.0142x over previous
//
#include <hip/hip_runtime.h>
#include <cstdint>
#include <cstddef>

typedef __bf16 bf16x8 __attribute__((ext_vector_type(8)));
typedef __bf16 bf16x4 __attribute__((ext_vector_type(4)));
typedef float  f32x4  __attribute__((ext_vector_type(4)));

#define MFMA16(a,b,c) __builtin_amdgcn_mfma_f32_16x16x32_bf16((a),(b),(c),0,0,0)

#define BAR_LGKM() __asm__ volatile("s_waitcnt lgkmcnt(0)\n\ts_barrier" ::: "memory")
#define BAR_FULL() __asm__ volatile("s_waitcnt vmcnt(0) lgkmcnt(0)\n\ts_barrier" ::: "memory")

#define L2E  1.4426950408889634f   // log2(e)
#define L2E2 2.8853900817779268f   // 2*log2(e)

// Problem: B=256, T=512, D=H=128, 3H=384. x/out batch stride = 65536 elems.
// 32 blocks: 0..15 layer 0 (producer), 16..31 layer 1 (consumer, lagged).
// h0 crosses XCDs via nt stores/loads + per-pair agent-scope flags.
//
// Round-7 (on the round-5 base, round-6 specialization reverted):
//  1) WAVE-PHASE STAGGER: even waves rec->xp, odd waves xp->rec. On each
//     SIMD the odd wave's independent xp MFMAs fill the matrix pipe while
//     the even wave's dependent rec chain stalls, and the epilogue VALU of
//     one overlaps the MFMA burst of the other (lockstep forbade this).
//  2) POLL DECIMATION: layer-1 reads the remote progress flag only every
//     4th step (need=t+8) -- the agent-scope cross-XCD load was on the
//     consumer critical path every step.
//  3) C-INIT FUSION: first rec MFMA consumes the xp carry directly as C;
//     first xp MFMA consumes the zero vector directly (drops ~20 v_mov/step).

// ---------------------------------------------------------------------------
// prep_frags: stacked-weight B-frags, K=256 ([W(128) ; U(128)]), + flag init.
// Frag layout (16x16x32): B[k][n], n = lane&15, k = kt*32 + (lane>>4)*8 + j.
// Elem offset = ((ct*8+kt)*64 + lane)*8 + j, ct 0..23 (z:0-7,r:8-15,h:16-23),
// kt 0..7 (kt<4 -> W rows k, kt>=4 -> U rows k-128). Per layer: 98304 bf16.
// Values pre-scaled: L2E for z/r cols (ct<16), L2E2 for h cols (ct>=16).
// ---------------------------------------------------------------------------
__global__ void prep_frags(const float* __restrict__ W0, const float* __restrict__ U0,
                           const float* __restrict__ W1, const float* __restrict__ U1,
                           __bf16* __restrict__ frags, int* __restrict__ flags)
{
    if (blockIdx.x == 0 && threadIdx.x < 16) flags[threadIdx.x * 16] = 0;
    int id = blockIdx.x * 512 + threadIdx.x;      // 0..24575
    int layer = id / 12288;
    int r     = id % 12288;                       // (ct*8+kt)*64 + lane
    int lane = r & 63;
    int ctkt = r >> 6;                            // 0..191
    int kt = ctkt & 7;
    int ct = ctkt >> 3;
    const float* Wsrc = layer ? W1 : W0;
    const float* Usrc = layer ? U1 : U0;
    int n  = ct * 16 + (lane & 15);
    int k0 = kt * 32 + (lane >> 4) * 8;           // never straddles 128
    const float* src = (k0 < 128) ? (Wsrc + (size_t)k0 * 384)
                                  : (Usrc + (size_t)(k0 - 128) * 384);
    const float s = (ct < 16) ? L2E : L2E2;       // z,r vs h columns
    __bf16* dst = frags + (size_t)layer * 98304 + (size_t)r * 8;
#pragma unroll
    for (int j = 0; j < 8; j++)
        dst[j] = (__bf16)(src[(size_t)j * 384 + n] * s);
}

// ---------------------------------------------------------------------------
// gru_pipe: per block 16 batch rows, 512 threads (8 waves, 2/SIMD). Wave w
// owns hidden col j=16w+l15 for all gates. Per step t:
//   rec: az/ar (C-init = xp carry) += h_{t-1}.U ; ahh = h-gate rec part
//   xp:  xp_{t+2} = x_{t+2}.W  (independent; order staggered by wave parity)
// Producer publishes flag=t every 4th step after a FULL drain: flag F
// asserts h0 steps 0..F-1 are in HBM. Consumer polls every 4th step for
// flag >= t+8 (covers prefetch t+4..t+7); prologue gates on flag >= 8.
// h0 may alias out (small-ws fallback): consumer reads slot t+4 strictly
// before overwriting slot t. No __restrict__ on x/h0/out.
// ---------------------------------------------------------------------------
__global__ __launch_bounds__(512, 2) void gru_pipe(
    const float* x, const __bf16* __restrict__ frags,
    const float* __restrict__ b0, const float* __restrict__ b1,
    float* h0, float* out, int* flags)
{
    __shared__ __align__(16) __bf16 xb[2][2048];   // x_{t+2} tiles (ring of 2)
    __shared__ __align__(16) __bf16 hb[2][2048];   // h double buffer

    const int tid  = threadIdx.x;
    const int wave = tid >> 6, lane = tid & 63;
    const int l15  = lane & 15, quad = lane >> 4;
    const int pair  = blockIdx.x & 15;
    const int layer = blockIdx.x >> 4;
    const int B0 = pair * 16;
    int* const flagp = flags + pair * 16;          // one 64B line per pair

    const __bf16* Bf  = frags + (size_t)layer * 98304;
    const float* bias = layer ? b1 : b0;
    const float* xin  = layer ? h0 : x;
    float*       hout = layer ? out : h0;

    // persistent B-frags: W part (kt 0..3) and U part (kt 4..7), pinned so
    // the loads cannot be sunk into the t-loop (round-4 lesson).
    bf16x8 bw[3][4], bu[3][4];
#pragma unroll
    for (int g = 0; g < 3; g++) {
        int ct = 8 * g + wave;
#pragma unroll
        for (int kt = 0; kt < 4; kt++) {
            bw[g][kt] = *(const bf16x8*)(Bf + (size_t)((ct * 8 + kt) * 64 + lane) * 8);
            bu[g][kt] = *(const bf16x8*)(Bf + (size_t)((ct * 8 + kt + 4) * 64 + lane) * 8);
            __asm__ volatile("" : "+v"(bw[g][kt]));
            __asm__ volatile("" : "+v"(bu[g][kt]));
        }
    }

    const int j = wave * 16 + l15;
    const float bz  = (bias[j]       + bias[384 + j]) * L2E;
    const float br  = (bias[128 + j] + bias[512 + j]) * L2E;
    const float bxh = bias[256 + j] * L2E2;
    const float brh = bias[640 + j] * L2E2;

    // staging map: 512 threads cover 16 rows x 128 cols (4 floats each)
    const int srow = tid >> 5;
    const float* px = xin + (size_t)(B0 + srow) * 65536 + (tid & 31) * 4;
    const int sb = (srow * 256 + (tid & 31) * 8) ^ ((srow & 7) << 4);

    // A-frag byte offsets: row l15, k-cols quad*8 + kt*32 (bf16) -> bytes
    const int swz = (l15 & 7) << 4;
    const int abb = l15 * 256 + quad * 16;
    const int ao0 = (abb      ) ^ swz;
    const int ao1 = (abb +  64) ^ swz;
    const int ao2 = (abb + 128) ^ swz;
    const int ao3 = (abb + 192) ^ swz;
    // h-write byte offsets (scalar bf16, row = quad*4+r, col j)
    int hw_[4];
#pragma unroll
    for (int r = 0; r < 4; r++) {
        int row = quad * 4 + r;
        hw_[r] = (row * 256 + j * 2) ^ ((row & 7) << 4);
    }

    const size_t obase = (size_t)(B0 + quad * 4) * 65536 + j;

    int known = 0;
    if (layer) {                 // prologue + step 0..3 prefetch window
        while (known < 8) {
            __builtin_amdgcn_s_sleep(4);
            known = __hip_atomic_load(flagp, __ATOMIC_RELAXED,
                                      __HIP_MEMORY_SCOPE_AGENT);
        }
    }

#define LOADX(p) (layer ? __builtin_nontemporal_load((const f32x4*)(p)) \
                        : *(const f32x4*)(p))
#define PACKST(buf, v) do { bf16x4 hv_;                                  \
        hv_.x = (__bf16)(v)[0]; hv_.y = (__bf16)(v)[1];                  \
        hv_.z = (__bf16)(v)[2]; hv_.w = (__bf16)(v)[3];                  \
        *(bf16x4*)((char*)&(buf)[0] + sb) = hv_; } while (0)

    const f32x4 zv = {0.f, 0.f, 0.f, 0.f};

    // ---- prologue: stage x_0,x_1; zero h; compute xp_0, xp_1; stage x_2 ----
    {
        f32x4 v0 = LOADX(px);
        f32x4 v1 = LOADX(px + 128);
        PACKST(xb[0], v0);
        PACKST(xb[1], v1);
        ((uint64_t*)&hb[0][0])[tid] = 0ull;        // 4096 B = 512 x 8B
    }
    __syncthreads();

    f32x4 xpzE = zv, xprE = zv, xphE = zv;         // xp_0 (even set)
    f32x4 xpzO = zv, xprO = zv, xphO = zv;         // xp_1 (odd set)
    {
        bf16x8 Ax0 = *(const bf16x8*)((const char*)&xb[0][0] + ao0);
        bf16x8 Ax1 = *(const bf16x8*)((const char*)&xb[0][0] + ao1);
        bf16x8 Ax2 = *(const bf16x8*)((const char*)&xb[0][0] + ao2);
        bf16x8 Ax3 = *(const bf16x8*)((const char*)&xb[0][0] + ao3);
        xpzE = MFMA16(Ax0, bw[0][0], xpzE); xprE = MFMA16(Ax0, bw[1][0], xprE); xphE = MFMA16(Ax0, bw[2][0], xphE);
        xpzE = MFMA16(Ax1, bw[0][1], xpzE); xprE = MFMA16(Ax1, bw[1][1], xprE); xphE = MFMA16(Ax1, bw[2][1], xphE);
        xpzE = MFMA16(Ax2, bw[0][2], xpzE); xprE = MFMA16(Ax2, bw[1][2], xprE); xphE = MFMA16(Ax2, bw[2][2], xphE);
        xpzE = MFMA16(Ax3, bw[0][3], xpzE); xprE = MFMA16(Ax3, bw[1][3], xprE); xphE = MFMA16(Ax3, bw[2][3], xphE);
    }
    {
        bf16x8 Ax0 = *(const bf16x8*)((const char*)&xb[1][0] + ao0);
        bf16x8 Ax1 = *(const bf16x8*)((const char*)&xb[1][0] + ao1);
        bf16x8 Ax2 = *(const bf16x8*)((const char*)&xb[1][0] + ao2);
        bf16x8 Ax3 = *(const bf16x8*)((const char*)&xb[1][0] + ao3);
        xpzO = MFMA16(Ax0, bw[0][0], xpzO); xprO = MFMA16(Ax0, bw[1][0], xprO); xphO = MFMA16(Ax0, bw[2][0], xphO);
        xpzO = MFMA16(Ax1, bw[0][1], xpzO); xprO = MFMA16(Ax1, bw[1][1], xprO); xphO = MFMA16(Ax1, bw[2][1], xphO);
        xpzO = MFMA16(Ax2, bw[0][2], xpzO); xprO = MFMA16(Ax2, bw[1][2], xprO); xphO = MFMA16(Ax2, bw[2][2], xphO);
        xpzO = MFMA16(Ax3, bw[0][3], xpzO); xprO = MFMA16(Ax3, bw[1][3], xprO); xphO = MFMA16(Ax3, bw[2][3], xphO);
    }
    __syncthreads();                                // all reads of xb[0] done
    {
        f32x4 v2 = LOADX(px + 256);                 // x_2 -> slot 0
        PACKST(xb[0], v2);
    }
    f32x4 vc = LOADX(px + 384);                     // x_3 (staged at t=0)
    float hold[4] = {0.f, 0.f, 0.f, 0.f};
    __syncthreads();

// layer-1 flag poll, only on (t&3)==0 steps, covering prefetch t+4..t+7
#define POLL4(t_)                                                             \
        if (layer && (((t_) & 3) == 0)) {                                     \
            int need = (t_) + 8; if (need > 512) need = 512;                   \
            while (known < need) {                                            \
                __builtin_amdgcn_s_sleep(4);                                  \
                known = __hip_atomic_load(flagp, __ATOMIC_RELAXED,            \
                                          __HIP_MEMORY_SCOPE_AGENT);          \
            }                                                                 \
        }

// shared tail: epilogue + stage + barrier/publish + global stores
#define GRU_TAIL(t_, S, azv, arv, xhcv, ahhv)                                 \
        float hnew[4];                                                        \
        _Pragma("unroll")                                                     \
        for (int r = 0; r < 4; r++) {                                         \
            float z  = __builtin_amdgcn_rcpf(                                 \
                           1.f + __builtin_amdgcn_exp2f(-((azv)[r] + bz)));   \
            float rg = __builtin_amdgcn_rcpf(                                 \
                           1.f + __builtin_amdgcn_exp2f(-((arv)[r] + br)));   \
            float hp = ((xhcv)[r] + bxh) + rg * ((ahhv)[r] + brh);            \
            float e2 = __builtin_amdgcn_exp2f(hp);                            \
            float th = 1.f - 2.f * __builtin_amdgcn_rcpf(e2 + 1.f);           \
            hnew[r] = th + z * (hold[r] - th);                                \
            hold[r] = hnew[r];                                                \
        }                                                                     \
        PACKST(xb[(S) ^ 1], vc);                                              \
        _Pragma("unroll")                                                     \
        for (int r = 0; r < 4; r++)                                           \
            *(__bf16*)((char*)&hb[(S) ^ 1][0] + hw_[r]) = (__bf16)hnew[r];    \
        if (layer == 0 && ((t_) & 3) == 3) {                                  \
            BAR_FULL();               /* h0 stores of steps <= t-1 in HBM */  \
            if (tid == 0)                                                     \
                __hip_atomic_store(flagp, t_, __ATOMIC_RELAXED,               \
                                   __HIP_MEMORY_SCOPE_AGENT);                 \
        } else {                                                              \
            BAR_LGKM();                                                       \
        }                                                                     \
        if (layer == 0) {                                                     \
            _Pragma("unroll")                                                 \
            for (int r = 0; r < 4; r++)                                       \
                __builtin_nontemporal_store(hnew[r],                          \
                    hout + obase + (size_t)r * 65536 + (size_t)t_ * 128);     \
        } else {                                                              \
            _Pragma("unroll")                                                 \
            for (int r = 0; r < 4; r++)                                       \
                hout[obase + (size_t)r * 65536 + (size_t)t_ * 128] = hnew[r]; \
        }                                                                     \
        vc = vn;

// rec-first body (even waves): rec chain -> xp group -> epilogue
#define GRU_RF(T, S, xpz, xpr, xph)                                           \
    {                                                                         \
        const int t_ = (T);                                                   \
        POLL4(t_);                                                            \
        int t4_ = t_ + 4; if (t4_ > 511) t4_ = 511;                           \
        f32x4 vn = LOADX(px + (size_t)t4_ * 128);                             \
        bf16x8 Ah0 = *(const bf16x8*)((const char*)&hb[S][0] + ao0);          \
        bf16x8 Ah1 = *(const bf16x8*)((const char*)&hb[S][0] + ao1);          \
        bf16x8 Ah2 = *(const bf16x8*)((const char*)&hb[S][0] + ao2);          \
        bf16x8 Ah3 = *(const bf16x8*)((const char*)&hb[S][0] + ao3);          \
        __builtin_amdgcn_s_setprio(1);                                        \
        f32x4 az  = MFMA16(Ah0, bu[0][0], xpz);                               \
        f32x4 ar  = MFMA16(Ah0, bu[1][0], xpr);                               \
        f32x4 ahh = MFMA16(Ah0, bu[2][0], zv);                                \
        az = MFMA16(Ah1, bu[0][1], az); ar = MFMA16(Ah1, bu[1][1], ar);       \
        ahh = MFMA16(Ah1, bu[2][1], ahh);                                     \
        az = MFMA16(Ah2, bu[0][2], az); ar = MFMA16(Ah2, bu[1][2], ar);       \
        ahh = MFMA16(Ah2, bu[2][2], ahh);                                     \
        az = MFMA16(Ah3, bu[0][3], az); ar = MFMA16(Ah3, bu[1][3], ar);       \
        ahh = MFMA16(Ah3, bu[2][3], ahh);                                     \
        bf16x8 Ax0 = *(const bf16x8*)((const char*)&xb[S][0] + ao0);          \
        bf16x8 Ax1 = *(const bf16x8*)((const char*)&xb[S][0] + ao1);          \
        bf16x8 Ax2 = *(const bf16x8*)((const char*)&xb[S][0] + ao2);          \
        bf16x8 Ax3 = *(const bf16x8*)((const char*)&xb[S][0] + ao3);          \
        f32x4 xhc = xph;                          /* xp_t h-part for epi */   \
        xpz = MFMA16(Ax0, bw[0][0], zv);  xpr = MFMA16(Ax0, bw[1][0], zv);    \
        xph = MFMA16(Ax0, bw[2][0], zv);                                      \
        xpz = MFMA16(Ax1, bw[0][1], xpz); xpr = MFMA16(Ax1, bw[1][1], xpr);   \
        xph = MFMA16(Ax1, bw[2][1], xph);                                     \
        xpz = MFMA16(Ax2, bw[0][2], xpz); xpr = MFMA16(Ax2, bw[1][2], xpr);   \
        xph = MFMA16(Ax2, bw[2][2], xph);                                     \
        xpz = MFMA16(Ax3, bw[0][3], xpz); xpr = MFMA16(Ax3, bw[1][3], xpr);   \
        xph = MFMA16(Ax3, bw[2][3], xph);                                     \
        __builtin_amdgcn_s_setprio(0);                                        \
        GRU_TAIL(t_, S, az, ar, xhc, ahh)                                     \
    }

// xp-first body (odd waves): xp group -> rec chain -> epilogue
#define GRU_XF(T, S, xpz, xpr, xph)                                           \
    {                                                                         \
        const int t_ = (T);                                                   \
        POLL4(t_);                                                            \
        int t4_ = t_ + 4; if (t4_ > 511) t4_ = 511;                           \
        f32x4 vn = LOADX(px + (size_t)t4_ * 128);                             \
        bf16x8 Ax0 = *(const bf16x8*)((const char*)&xb[S][0] + ao0);          \
        bf16x8 Ax1 = *(const bf16x8*)((const char*)&xb[S][0] + ao1);          \
        bf16x8 Ax2 = *(const bf16x8*)((const char*)&xb[S][0] + ao2);          \
        bf16x8 Ax3 = *(const bf16x8*)((const char*)&xb[S][0] + ao3);          \
        __builtin_amdgcn_s_setprio(1);                                        \
        f32x4 tz = MFMA16(Ax0, bw[0][0], zv);                                 \
        f32x4 tr = MFMA16(Ax0, bw[1][0], zv);                                 \
        f32x4 th2 = MFMA16(Ax0, bw[2][0], zv);                                \
        tz = MFMA16(Ax1, bw[0][1], tz); tr = MFMA16(Ax1, bw[1][1], tr);       \
        th2 = MFMA16(Ax1, bw[2][1], th2);                                     \
        tz = MFMA16(Ax2, bw[0][2], tz); tr = MFMA16(Ax2, bw[1][2], tr);       \
        th2 = MFMA16(Ax2, bw[2][2], th2);                                     \
        tz = MFMA16(Ax3, bw[0][3], tz); tr = MFMA16(Ax3, bw[1][3], tr);       \
        th2 = MFMA16(Ax3, bw[2][3], th2);                                     \
        bf16x8 Ah0 = *(const bf16x8*)((const char*)&hb[S][0] + ao0);          \
        bf16x8 Ah1 = *(const bf16x8*)((const char*)&hb[S][0] + ao1);          \
        bf16x8 Ah2 = *(const bf16x8*)((const char*)&hb[S][0] + ao2);          \
        bf16x8 Ah3 = *(const bf16x8*)((const char*)&hb[S][0] + ao3);          \
        f32x4 az  = MFMA16(Ah0, bu[0][0], xpz);                               \
        f32x4 ar  = MFMA16(Ah0, bu[1][0], xpr);                               \
        f32x4 ahh = MFMA16(Ah0, bu[2][0], zv);                                \
        az = MFMA16(Ah1, bu[0][1], az); ar = MFMA16(Ah1, bu[1][1], ar);       \
        ahh = MFMA16(Ah1, bu[2][1], ahh);                                     \
        az = MFMA16(Ah2, bu[0][2], az); ar = MFMA16(Ah2, bu[1][2], ar);       \
        ahh = MFMA16(Ah2, bu[2][2], ahh);                                     \
        az = MFMA16(Ah3, bu[0][3], az); ar = MFMA16(Ah3, bu[1][3], ar);       \
        ahh = MFMA16(Ah3, bu[2][3], ahh);                                     \
        __builtin_amdgcn_s_setprio(0);                                        \
        GRU_TAIL(t_, S, az, ar, xph, ahh)                                     \
        xpz = tz; xpr = tr; xph = th2;                                        \
    }

    if ((wave & 1) == 0) {
        for (int it = 0; it < 256; ++it) {
            GRU_RF(2 * it,     0, xpzE, xprE, xphE);
            GRU_RF(2 * it + 1, 1, xpzO, xprO, xphO);
        }
    } else {
        for (int it = 0; it < 256; ++it) {
            GRU_XF(2 * it,     0, xpzE, xprE, xphE);
            GRU_XF(2 * it + 1, 1, xpzO, xprO, xphO);
        }
    }
#undef GRU_RF
#undef GRU_XF
#undef GRU_TAIL
#undef POLL4
#undef PACKST
#undef LOADX

    if (layer == 0) {
        BAR_FULL();        // drain final h0 stores (incl. step 511)
        if (tid == 0)
            __hip_atomic_store(flagp, 512, __ATOMIC_RELAXED,
                               __HIP_MEMORY_SCOPE_AGENT);
    }
}

// ---------------------------------------------------------------------------
extern "C" void kernel_launch(void* const* d_in, const int* in_sizes, int n_in,
                              void* d_out, int out_size, void* d_ws, size_t ws_size,
                              hipStream_t stream)
{
    const float* x  = (const float*)d_in[0];
    const float* W0 = (const float*)d_in[1];
    const float* U0 = (const float*)d_in[2];
    const float* b0 = (const float*)d_in[3];
    const float* W1 = (const float*)d_in[4];
    const float* U1 = (const float*)d_in[5];
    const float* b1 = (const float*)d_in[6];
    float* out = (float*)d_out;

    char* ws = (char*)d_ws;
    __bf16* frags = (__bf16*)ws;                 // 2 * 98304 bf16 = 393,216 B
    int*    flags = (int*)(ws + 393216);         // 16 pairs x 64 B = 1024 B
    // h0 at ws + 448 KiB if it fits, else alias d_out (pipeline-safe: consumer
    // reads slot t+4 strictly before overwriting slot t).
    float* h0;
    const size_t need = 458752 + 67108864;
    if (ws_size >= need) h0 = (float*)(ws + 458752);
    else                 h0 = out;

    prep_frags<<<48, 512, 0, stream>>>(W0, U0, W1, U1, frags, flags);
    gru_pipe<<<32, 512, 0, stream>>>(x, frags, b0, b1, h0, out, flags);
}